// Round 4
// baseline (517.992 us; speedup 1.0000x reference)
//
#include <hip/hip_runtime.h>
#include <hip/hip_bf16.h>
#include <math.h>

#define D 256
#define H 4
#define DH 64
#define NOUT 256

typedef short bf16x8 __attribute__((ext_vector_type(8)));
typedef float f32x4 __attribute__((ext_vector_type(4)));

__device__ __forceinline__ ushort f2bf(float f){
  uint b = __float_as_uint(f);
  b += 0x7FFF + ((b >> 16) & 1);   // round-to-nearest-even
  return (ushort)(b >> 16);
}
__device__ __forceinline__ float bf2f(ushort u){
  return __uint_as_float(((uint)u) << 16);
}

// DPP-based sum reduction over 32 lanes (rows of 16 via row_ror, then xor-16).
__device__ __forceinline__ float redux32(float v){
  int t;
  t = __builtin_amdgcn_update_dpp(0, __float_as_int(v), 0x121, 0xF, 0xF, true); v += __int_as_float(t); // row_ror:1
  t = __builtin_amdgcn_update_dpp(0, __float_as_int(v), 0x122, 0xF, 0xF, true); v += __int_as_float(t); // row_ror:2
  t = __builtin_amdgcn_update_dpp(0, __float_as_int(v), 0x124, 0xF, 0xF, true); v += __int_as_float(t); // row_ror:4
  t = __builtin_amdgcn_update_dpp(0, __float_as_int(v), 0x128, 0xF, 0xF, true); v += __int_as_float(t); // row_ror:8
  v += __shfl_xor(v, 16, 64);
  return v;
}

// ---------------- CSR build ----------------
__global__ void count_winner_kernel(const int* __restrict__ seg, int* __restrict__ counts,
                                    const int* __restrict__ pdgkey, int* __restrict__ winner,
                                    int M, int C){
  int i = blockIdx.x*256 + threadIdx.x;
  if (i < M){ int s = seg[i]; if (s >= 0 && s < C) atomicAdd(&counts[s], 1); }
  if (i < C){ int t = pdgkey[i]; if (t >= 0 && t < C) atomicMax(&winner[t], i); }
}

__global__ __launch_bounds__(1024) void scan1_kernel(const int* __restrict__ counts,
    int* __restrict__ loc, int* __restrict__ btot, int C){
  __shared__ int wtot[16];
  __shared__ int wexcl[16];
  int tid = threadIdx.x, lane = tid & 63, wv = tid >> 6;
  int i = blockIdx.x*1024 + tid;
  int v = (i < C) ? counts[i] : 0;
  int x = v;
  #pragma unroll
  for (int d2 = 1; d2 < 64; d2 <<= 1){
    int t = __shfl_up(x, d2, 64);
    if (lane >= d2) x += t;
  }
  if (lane == 63) wtot[wv] = x;
  __syncthreads();
  if (wv == 0 && lane < 16){
    int t = wtot[lane]; int y = t;
    #pragma unroll
    for (int d2 = 1; d2 < 16; d2 <<= 1){
      int u = __shfl_up(y, d2, 64);
      if (lane >= d2) y += u;
    }
    wexcl[lane] = y - t;
    if (lane == 15) btot[blockIdx.x] = y;
  }
  __syncthreads();
  if (i < C) loc[i] = wexcl[wv] + x - v;
}

__global__ void scan2_kernel(const int* __restrict__ btot, int* __restrict__ bexcl,
                             int nb, int* __restrict__ offsets, int C){
  int lane = threadIdx.x;             // 64 threads, nb <= 64
  int v = (lane < nb) ? btot[lane] : 0;
  int x = v;
  #pragma unroll
  for (int d2 = 1; d2 < 64; d2 <<= 1){
    int t = __shfl_up(x, d2, 64);
    if (lane >= d2) x += t;
  }
  if (lane < nb) bexcl[lane] = x - v;
  if (lane == 63) offsets[C] = x;     // grand total
}

__global__ void scan3_kernel(const int* __restrict__ loc, const int* __restrict__ bexcl,
                             int* __restrict__ offsets, int* __restrict__ pos, int C){
  int i = blockIdx.x*256 + threadIdx.x;
  if (i < C){ int o = loc[i] + bexcl[i >> 10]; offsets[i] = o; pos[i] = o; }
}

// rows[p] = astkey[i]: store the enc row id directly.
__global__ void fill_kernel(const int* __restrict__ seg, const int* __restrict__ astkey,
                            int* __restrict__ pos, int* __restrict__ rows, int M, int C){
  int i = blockIdx.x*256 + threadIdx.x;
  if (i < M){
    int s = seg[i];
    if (s >= 0 && s < C){ int p = atomicAdd(&pos[s], 1); rows[p] = astkey[i]; }
  }
}

// ---------------- merged weight prep ----------------
__global__ __launch_bounds__(256) void prep_weights(
    const float* __restrict__ Wq, const float* __restrict__ Wk,
    const float* __restrict__ Wv, const float* __restrict__ Wo,
    const float* __restrict__ bq, const float* __restrict__ bk,
    const float* __restrict__ bv,
    ushort* __restrict__ Wq16, ushort* __restrict__ Wk16, ushort* __restrict__ Wv16,
    ushort* __restrict__ WoT16,
    float* __restrict__ wqbk, float* __restrict__ bvo,
    float* __restrict__ bqk, float* __restrict__ cbh){
  __shared__ float t[64][65];
  int bid = blockIdx.x, tid = threadIdx.x;
  if (bid < 256){
    int id = bid*256 + tid;
    Wq16[id] = f2bf(Wq[id]);
    Wk16[id] = f2bf(Wk[id]);
    Wv16[id] = f2bf(Wv[id]);
  } else if (bid < 269){
    int id = (bid - 256)*256 + tid;
    if (id < 1024){
      int h = id >> 8, k = id & 255;
      float s = 0.f;
      for (int d = 0; d < DH; d++) s += Wq[(size_t)k*256 + h*64 + d] * bk[h*64 + d];
      wqbk[id] = s;
    } else if (id < 2048){
      int tt = id - 1024; int h = tt >> 8, o = tt & 255;
      float s = 0.f;
      for (int d = 0; d < DH; d++) s += bv[h*64 + d] * Wo[(size_t)(h*64 + d)*256 + o];
      bvo[tt] = s;
    } else if (id < 3072){
      int tt = id - 2048; int h = tt >> 8, e = tt & 255;
      float s = 0.f;
      for (int d = 0; d < DH; d++) s += bq[h*64 + d] * Wk[(size_t)e*256 + h*64 + d];
      bqk[tt] = s;
    } else if (id < 3076){
      int h = id - 3072;
      float s = 0.f;
      for (int d = 0; d < DH; d++) s += bq[h*64 + d] * bk[h*64 + d];
      cbh[h] = s;
    }
  } else {
    int b2 = bid - 269;
    int bx = b2 & 3, by = b2 >> 2;
    int r = tid >> 6, cc = tid & 63;
    #pragma unroll
    for (int rr = 0; rr < 64; rr += 4)
      t[rr + r][cc] = Wo[(size_t)(by*64 + rr + r)*256 + bx*64 + cc];
    __syncthreads();
    #pragma unroll
    for (int rr = 0; rr < 64; rr += 4)
      WoT16[(size_t)(bx*64 + rr + r)*256 + by*64 + cc] = f2bf(t[cc][rr + r]);
  }
}

// ---------------- gather attn_keys rows -> bf16 A matrix + qb precompute ----------------
__global__ void gather_ag(const float* __restrict__ enc, const int* __restrict__ rootval,
                          const int* __restrict__ winner,
                          const float* __restrict__ wqbk, const float* __restrict__ cbh,
                          ushort* __restrict__ Ag, float* __restrict__ qb, int C){
  int id = blockIdx.x*256 + threadIdx.x;      // C*64 total
  int c = id >> 6, g = id & 63;
  if (c >= C) return;
  int w = winner[c];
  float4 v = make_float4(0.f, 0.f, 0.f, 0.f);
  if (w >= 0) v = *(const float4*)(enc + (size_t)rootval[w]*D + g*4);
  ushort4 u; u.x = f2bf(v.x); u.y = f2bf(v.y); u.z = f2bf(v.z); u.w = f2bf(v.w);
  *(ushort4*)(Ag + (size_t)c*D + g*4) = u;
  float b0 = bf2f(u.x), b1 = bf2f(u.y), b2 = bf2f(u.z), b3 = bf2f(u.w);
  float pv[4];
  #pragma unroll
  for (int h = 0; h < 4; h++){
    float4 wv = *(const float4*)(wqbk + h*256 + g*4);
    float p = b0*wv.x + b1*wv.y + b2*wv.z + b3*wv.w;
    p = redux32(p);
    p += __shfl_xor(p, 32, 64);
    pv[h] = p;
  }
  if (g < 4) qb[c*4 + g] = pv[g] + cbh[g];
}

// ---------------- small bf16 MFMA GEMM (weight prep only) ----------------
template<bool OUT_BF16>
__global__ __launch_bounds__(256) void mfma_gemm(
    const ushort* __restrict__ A, int sA, int acol_h,
    const ushort* __restrict__ Bt, int sBt, int btrow_h, int btcol_h,
    void* __restrict__ Out, int sOut, int outrow_h, int outcol_h,
    int M, int K,
    const float* __restrict__ bias, const float* __restrict__ beta4,
    const float* __restrict__ bvo4){
  __shared__ __align__(16) ushort As[64][72];
  __shared__ __align__(16) ushort Bs[64][72];
  int tid = threadIdx.x;
  int hz = blockIdx.z;
  int m0 = blockIdx.x*64;
  int acol0  = acol_h*hz;
  int btrow0 = blockIdx.y*64 + btrow_h*hz;
  int btcol0 = btcol_h*hz;
  int outrow0 = outrow_h*hz;
  int outcol0 = blockIdx.y*64 + outcol_h*hz;
  int w = tid >> 6, lane = tid & 63, quad = lane >> 4, l16 = lane & 15;
  int r1 = tid >> 3, c8 = (tid & 7)*8;
  f32x4 acc[4] = {};
  for (int k0 = 0; k0 < K; k0 += 64){
    const ushort* ga = A + (size_t)(m0 + r1)*sA + acol0 + k0 + c8;
    uint4 v1 = make_uint4(0,0,0,0), v2 = make_uint4(0,0,0,0);
    if (m0 + r1 < M)      v1 = *(const uint4*)ga;
    if (m0 + r1 + 32 < M) v2 = *(const uint4*)(ga + (size_t)32*sA);
    *(uint4*)&As[r1][c8]      = v1;
    *(uint4*)&As[r1+32][c8]   = v2;
    const ushort* gb = Bt + (size_t)(btrow0 + r1)*sBt + btcol0 + k0 + c8;
    *(uint4*)&Bs[r1][c8]      = *(const uint4*)gb;
    *(uint4*)&Bs[r1+32][c8]   = *(const uint4*)(gb + (size_t)32*sBt);
    __syncthreads();
    #pragma unroll
    for (int ks = 0; ks < 2; ks++){
      bf16x8 b = *(const bf16x8*)&Bs[w*16 + l16][ks*32 + quad*8];
      #pragma unroll
      for (int mt = 0; mt < 4; mt++){
        bf16x8 a = *(const bf16x8*)&As[mt*16 + l16][ks*32 + quad*8];
        acc[mt] = __builtin_amdgcn_mfma_f32_16x16x32_bf16(a, b, acc[mt], 0, 0, 0);
      }
    }
    __syncthreads();
  }
  int col = outcol0 + w*16 + l16;
  int bcol = btrow0 + w*16 + l16;
  float bval = bias ? bias[bcol] : 0.f;
  #pragma unroll
  for (int mt = 0; mt < 4; mt++){
    #pragma unroll
    for (int r = 0; r < 4; r++){
      int row = m0 + mt*16 + quad*4 + r;
      if (row < M){
        float v = acc[mt][r] + bval;
        if (bvo4){
          v += beta4[row*4+0]*bvo4[0*256 + bcol] + beta4[row*4+1]*bvo4[1*256 + bcol]
             + beta4[row*4+2]*bvo4[2*256 + bcol] + beta4[row*4+3]*bvo4[3*256 + bcol];
        }
        if (OUT_BF16) ((ushort*)Out)[(size_t)(outrow0 + row)*sOut + col] = f2bf(v);
        else          ((float*)Out)[(size_t)(outrow0 + row)*sOut + col] = v;
      }
    }
  }
}

// ---------------- 128x128-tile bf16 MFMA GEMM (big GEMMs) ----------------
// Out[row, col] = sum_k A[row,k]*Bt[col,k] (+bias[col]) (+sum_h beta4[row*4+h]*bvo4[h*256+col])
// 4 waves in a 2x2 layout, each computing a 64x64 quadrant (4x4 frags of 16x16x32).
// A must be readable for ceil(M/128)*128 rows (caller pads the allocation);
// Bt must have exactly gridDim.y*128 rows; K a multiple of 64.
template<bool OUT_BF16>
__global__ __launch_bounds__(256) void gemm128(
    const ushort* __restrict__ A, int sA,
    const ushort* __restrict__ Bt, int sBt,
    void* __restrict__ Out, int sOut,
    int Mrows, int K,
    const float* __restrict__ bias, const float* __restrict__ beta4,
    const float* __restrict__ bvo4){
  __shared__ __align__(16) ushort As[128][72];
  __shared__ __align__(16) ushort Bs[128][72];
  int tid = threadIdx.x;
  int m0 = blockIdx.x*128, n0 = blockIdx.y*128;
  int wave = tid >> 6, lane = tid & 63, quad = lane >> 4, l16 = lane & 15;
  int wr = (wave >> 1)*64, wc = (wave & 1)*64;
  int r1 = tid >> 3, c8 = (tid & 7)*8;     // staging: 8 lanes/row (128B contiguous)
  f32x4 acc[4][4] = {};
  const ushort* ga0 = A + (size_t)(m0 + r1)*sA + c8;
  const ushort* gb0 = Bt + (size_t)(n0 + r1)*sBt + c8;
  for (int k0 = 0; k0 < K; k0 += 64){
    const ushort* ga = ga0 + k0;
    const ushort* gb = gb0 + k0;
    #pragma unroll
    for (int rr = 0; rr < 128; rr += 32){
      *(uint4*)&As[r1 + rr][c8] = *(const uint4*)(ga + (size_t)rr*sA);
      *(uint4*)&Bs[r1 + rr][c8] = *(const uint4*)(gb + (size_t)rr*sBt);
    }
    __syncthreads();
    #pragma unroll
    for (int ks = 0; ks < 2; ks++){
      bf16x8 b[4], a[4];
      #pragma unroll
      for (int nt = 0; nt < 4; nt++) b[nt] = *(const bf16x8*)&Bs[wc + nt*16 + l16][ks*32 + quad*8];
      #pragma unroll
      for (int mt = 0; mt < 4; mt++) a[mt] = *(const bf16x8*)&As[wr + mt*16 + l16][ks*32 + quad*8];
      #pragma unroll
      for (int mt = 0; mt < 4; mt++){
        #pragma unroll
        for (int nt = 0; nt < 4; nt++)
          acc[mt][nt] = __builtin_amdgcn_mfma_f32_16x16x32_bf16(a[mt], b[nt], acc[mt][nt], 0, 0, 0);
      }
    }
    __syncthreads();
  }
  #pragma unroll
  for (int nt = 0; nt < 4; nt++){
    int col = n0 + wc + nt*16 + l16;
    float bval = bias ? bias[col] : 0.f;
    float bv0 = 0.f, bv1 = 0.f, bv2 = 0.f, bv3 = 0.f;
    if (bvo4){
      bv0 = bvo4[0*256 + col]; bv1 = bvo4[1*256 + col];
      bv2 = bvo4[2*256 + col]; bv3 = bvo4[3*256 + col];
    }
    #pragma unroll
    for (int mt = 0; mt < 4; mt++){
      #pragma unroll
      for (int r = 0; r < 4; r++){
        int row = m0 + wr + mt*16 + quad*4 + r;
        if (row < Mrows){
          float v = acc[mt][nt][r] + bval;
          if (bvo4){
            v += beta4[row*4+0]*bv0 + beta4[row*4+1]*bv1
               + beta4[row*4+2]*bv2 + beta4[row*4+3]*bv3;
          }
          if (OUT_BF16) ((ushort*)Out)[(size_t)row*sOut + col] = f2bf(v);
          else          ((float*)Out)[(size_t)row*sOut + col] = v;
        }
      }
    }
  }
}

// ---------------- fused per-segment attention pooling ----------------
// One segment per HALF-WAVE (8 segments per 256-thread block).
__global__ __launch_bounds__(256) void seg_attn(const float* __restrict__ enc,
    const int* __restrict__ rows, const int* __restrict__ offsets,
    const ushort* __restrict__ qk16, const float* __restrict__ qb,
    ushort* __restrict__ Shat16, float* __restrict__ beta, int C){
  int lane = threadIdx.x & 63, wave = threadIdx.x >> 6;
  int half = lane >> 5, sl = lane & 31;
  int c = blockIdx.x*8 + wave*2 + half;
  if (c >= C) return;
  float qk[4][8];
  const ushort* qkp = qk16 + (size_t)c*1024 + sl*8;
  #pragma unroll
  for (int h = 0; h < 4; h++){
    uint4 u = *(const uint4*)(qkp + h*256);
    qk[h][0]=__uint_as_float(u.x<<16); qk[h][1]=__uint_as_float(u.x&0xffff0000u);
    qk[h][2]=__uint_as_float(u.y<<16); qk[h][3]=__uint_as_float(u.y&0xffff0000u);
    qk[h][4]=__uint_as_float(u.z<<16); qk[h][5]=__uint_as_float(u.z&0xffff0000u);
    qk[h][6]=__uint_as_float(u.w<<16); qk[h][7]=__uint_as_float(u.w&0xffff0000u);
  }
  float4 qbv = *(const float4*)(qb + (size_t)c*4);
  float qbh[4] = {qbv.x, qbv.y, qbv.z, qbv.w};
  int off = offsets[c];
  int n = offsets[c+1] - off;
  float S[4][8] = {};
  float l[4] = {0.f, 0.f, 0.f, 0.f};
  for (int base = 0; base < n; base += 32){
    int cnt = min(32, n - base);
    int xrow = 0;
    if (sl < cnt) xrow = rows[off + base + sl];
    int r0 = __shfl(xrow, half*32 + 0, 64);
    int r1 = __shfl(xrow, half*32 + ((cnt > 1) ? 1 : 0), 64);
    const float* p0 = enc + (size_t)r0*256 + sl*8;
    const float* p1 = enc + (size_t)r1*256 + sl*8;
    float4 xa0 = *(const float4*)p0, xa1 = *(const float4*)(p0 + 4);
    float4 xb0 = *(const float4*)p1, xb1 = *(const float4*)(p1 + 4);
    for (int j = 0; j < cnt; j += 2){
      float4 na0 = xa0, na1 = xa1, nb0 = xb0, nb1 = xb1;
      if (j + 2 < cnt){
        int rr0 = __shfl(xrow, half*32 + j + 2, 64);
        int rr1 = __shfl(xrow, half*32 + ((j + 3 < cnt) ? (j + 3) : (j + 2)), 64);
        const float* q0 = enc + (size_t)rr0*256 + sl*8;
        const float* q1 = enc + (size_t)rr1*256 + sl*8;
        na0 = *(const float4*)q0; na1 = *(const float4*)(q0 + 4);
        nb0 = *(const float4*)q1; nb1 = *(const float4*)(q1 + 4);
      }
      float xa[8] = {xa0.x, xa0.y, xa0.z, xa0.w, xa1.x, xa1.y, xa1.z, xa1.w};
      float xb[8] = {xb0.x, xb0.y, xb0.z, xb0.w, xb1.x, xb1.y, xb1.z, xb1.w};
      float pa[4], pb[4];
      #pragma unroll
      for (int h = 0; h < 4; h++){
        pa[h] = xa[0]*qk[h][0] + xa[1]*qk[h][1] + xa[2]*qk[h][2] + xa[3]*qk[h][3]
              + xa[4]*qk[h][4] + xa[5]*qk[h][5] + xa[6]*qk[h][6] + xa[7]*qk[h][7];
        pb[h] = xb[0]*qk[h][0] + xb[1]*qk[h][1] + xb[2]*qk[h][2] + xb[3]*qk[h][3]
              + xb[4]*qk[h][4] + xb[5]*qk[h][5] + xb[6]*qk[h][6] + xb[7]*qk[h][7];
      }
      #pragma unroll
      for (int h = 0; h < 4; h++){ pa[h] = redux32(pa[h]); pb[h] = redux32(pb[h]); }
      bool v1 = (j + 1) < cnt;
      float ea[4], eb[4];
      #pragma unroll
      for (int h = 0; h < 4; h++){
        ea[h] = __expf((pa[h] + qbh[h]) * 0.125f);
        eb[h] = v1 ? __expf((pb[h] + qbh[h]) * 0.125f) : 0.f;
      }
      #pragma unroll
      for (int h = 0; h < 4; h++){
        l[h] += ea[h] + eb[h];
        #pragma unroll
        for (int k = 0; k < 8; k++){
          S[h][k] += ea[h]*xa[k];
          S[h][k] += eb[h]*xb[k];
        }
      }
      xa0 = na0; xa1 = na1; xb0 = nb0; xb1 = nb1;
    }
  }
  float inv[4];
  #pragma unroll
  for (int h = 0; h < 4; h++) inv[h] = 1.f / (l[h] + 1e-9f);
  ushort* sp = Shat16 + (size_t)c*1024 + sl*8;
  #pragma unroll
  for (int h = 0; h < 4; h++){
    float ih = inv[h];
    uint4 o;
    o.x = (uint)f2bf(S[h][0]*ih) | ((uint)f2bf(S[h][1]*ih) << 16);
    o.y = (uint)f2bf(S[h][2]*ih) | ((uint)f2bf(S[h][3]*ih) << 16);
    o.z = (uint)f2bf(S[h][4]*ih) | ((uint)f2bf(S[h][5]*ih) << 16);
    o.w = (uint)f2bf(S[h][6]*ih) | ((uint)f2bf(S[h][7]*ih) << 16);
    *(uint4*)(sp + h*256) = o;
  }
  if (sl == 0){
    beta[c*4+0] = l[0] / (l[0] + 1e-9f);
    beta[c*4+1] = l[1] / (l[1] + 1e-9f);
    beta[c*4+2] = l[2] / (l[2] + 1e-9f);
    beta[c*4+3] = l[3] / (l[3] + 1e-9f);
  }
}

extern "C" void kernel_launch(void* const* d_in, const int* in_sizes, int n_in,
                              void* d_out, int out_size, void* d_ws, size_t ws_size,
                              hipStream_t stream) {
  const float* enc    = (const float*)d_in[0];
  const int*   astkey = (const int*)d_in[1];
  const int*   seg    = (const int*)d_in[2];
  const int*   pdgkey = (const int*)d_in[3];
  const int*   pdgval = (const int*)d_in[4];
  const float* Wq = (const float*)d_in[6];
  const float* bq = (const float*)d_in[7];
  const float* Wk = (const float*)d_in[8];
  const float* bk = (const float*)d_in[9];
  const float* Wv = (const float*)d_in[10];
  const float* bv = (const float*)d_in[11];
  const float* Wo = (const float*)d_in[12];
  const float* bo = (const float*)d_in[13];
  float* out = (float*)d_out;
  const int M = in_sizes[1];
  const int C = in_sizes[3];
  const int mt128 = (C + 127) / 128;
  const int Cpad = mt128 * 128;      // padded row count for gemm128 A-inputs

  char* p = (char*)d_ws;
  auto alloc = [&](size_t bytes) -> void* {
    void* r = (void*)p;
    p += (bytes + 255) / 256 * 256;
    return r;
  };
  ushort* Ag      = (ushort*)alloc((size_t)Cpad * D * 2);       // padded for gemm128
  ushort* qk16    = (ushort*)alloc((size_t)C * H * D * 2);
  ushort* Shat16  = (ushort*)alloc((size_t)Cpad * H * D * 2);   // padded for gemm128
  float*  beta    = (float*)alloc((size_t)C * H * 4);
  float*  qb      = (float*)alloc((size_t)C * H * 4);
  ushort* Wq16    = (ushort*)alloc((size_t)D * D * 2);
  ushort* Wk16    = (ushort*)alloc((size_t)D * D * 2);
  ushort* Wv16    = (ushort*)alloc((size_t)D * D * 2);
  ushort* WoT16   = (ushort*)alloc((size_t)D * D * 2);
  ushort* Gt16    = (ushort*)alloc((size_t)H * D * D * 2);
  ushort* Zt16    = (ushort*)alloc((size_t)D * H * D * 2);
  float*  wqbk    = (float*)alloc((size_t)H * D * 4);
  float*  bvo     = (float*)alloc((size_t)H * NOUT * 4);
  float*  bqk     = (float*)alloc((size_t)H * D * 4);
  float*  cbh     = (float*)alloc((size_t)H * 4);
  int*   winner   = (int*)alloc((size_t)C * 4);
  int*   counts   = (int*)alloc((size_t)C * 4);
  int*   loc      = (int*)alloc((size_t)C * 4);
  int*   btot     = (int*)alloc((size_t)64 * 4);
  int*   bexcl    = (int*)alloc((size_t)64 * 4);
  int*   offsets  = (int*)alloc((size_t)(C + 1) * 4);
  int*   pos      = (int*)alloc((size_t)C * 4);
  int*   rows     = (int*)alloc((size_t)M * 4);

  hipMemsetAsync(winner, 0xFF, (size_t)C * 4, stream);
  hipMemsetAsync(counts, 0, (size_t)C * 4, stream);

  int gC = (C + 255) / 256, gM = (M + 255) / 256;
  int gMC = ((M > C ? M : C) + 255) / 256;
  int nb1024 = (C + 1023) / 1024;
  count_winner_kernel<<<gMC, 256, 0, stream>>>(seg, counts, pdgkey, winner, M, C);
  scan1_kernel<<<nb1024, 1024, 0, stream>>>(counts, loc, btot, C);
  scan2_kernel<<<1, 64, 0, stream>>>(btot, bexcl, nb1024, offsets, C);
  scan3_kernel<<<gC, 256, 0, stream>>>(loc, bexcl, offsets, pos, C);
  fill_kernel<<<gM, 256, 0, stream>>>(seg, astkey, pos, rows, M, C);

  prep_weights<<<285, 256, 0, stream>>>(Wq, Wk, Wv, Wo, bq, bk, bv,
                                        Wq16, Wk16, Wv16, WoT16, wqbk, bvo, bqk, cbh);

  // Gt[(h,e)][k] = sum_d Wq[k,64h+d]*Wk[e,64h+d]
  mfma_gemm<true><<<dim3(4,4,4), 256, 0, stream>>>(
      Wk16, D, DH,  Wq16, D, 0, DH,  Gt16, D, D, 0,  D, DH, nullptr, nullptr, nullptr);
  // Zt[o][(h,j)] = sum_d Wv[j,64h+d]*Wo[64h+d,o]
  mfma_gemm<true><<<dim3(4,4,4), 256, 0, stream>>>(
      WoT16, D, DH,  Wv16, D, 0, DH,  Zt16, H*D, 0, D,  D, DH, nullptr, nullptr, nullptr);

  gather_ag<<<(C*64 + 255)/256, 256, 0, stream>>>(enc, pdgval, winner, wqbk, cbh,
                                                  Ag, qb, C);

  // qk16[c, h*256+e] = Ag[c,:] @ Gt[(h,e),:] + bqk[h*256+e]   (flat GEMM 25000x1024x256)
  gemm128<true><<<dim3(mt128, (H*D)/128), 256, 0, stream>>>(
      Ag, D,  Gt16, D,  qk16, H*D,  C, D,  bqk, nullptr, nullptr);

  seg_attn<<<(C + 7)/8, 256, 0, stream>>>(enc, rows, offsets, qk16, qb,
                                          Shat16, beta, C);

  // out[c,o] = Shat[c,:] @ Zt[o,:] + bo[o] + sum_h beta[c,h]*bvo[h,o]  (flat 25000x256x1024)
  gemm128<false><<<dim3(mt128, NOUT/128), 256, 0, stream>>>(
      Shat16, H*D,  Zt16, H*D,  out, NOUT,  C, H*D,  bo, beta, bvo);
}

// Round 5
// 499.132 us; speedup vs baseline: 1.0378x; 1.0378x over previous
//
#include <hip/hip_runtime.h>
#include <hip/hip_bf16.h>
#include <math.h>

#define D 256
#define H 4
#define DH 64
#define NOUT 256

typedef short bf16x8 __attribute__((ext_vector_type(8)));
typedef float f32x4 __attribute__((ext_vector_type(4)));

__device__ __forceinline__ ushort f2bf(float f){
  uint b = __float_as_uint(f);
  b += 0x7FFF + ((b >> 16) & 1);   // round-to-nearest-even
  return (ushort)(b >> 16);
}
__device__ __forceinline__ float bf2f(ushort u){
  return __uint_as_float(((uint)u) << 16);
}

// DPP-based sum reduction over 32 lanes (rows of 16 via row_ror, then xor-16).
__device__ __forceinline__ float redux32(float v){
  int t;
  t = __builtin_amdgcn_update_dpp(0, __float_as_int(v), 0x121, 0xF, 0xF, true); v += __int_as_float(t); // row_ror:1
  t = __builtin_amdgcn_update_dpp(0, __float_as_int(v), 0x122, 0xF, 0xF, true); v += __int_as_float(t); // row_ror:2
  t = __builtin_amdgcn_update_dpp(0, __float_as_int(v), 0x124, 0xF, 0xF, true); v += __int_as_float(t); // row_ror:4
  t = __builtin_amdgcn_update_dpp(0, __float_as_int(v), 0x128, 0xF, 0xF, true); v += __int_as_float(t); // row_ror:8
  v += __shfl_xor(v, 16, 64);
  return v;
}

// ---------------- CSR build ----------------
__global__ void count_winner_kernel(const int* __restrict__ seg, int* __restrict__ counts,
                                    const int* __restrict__ pdgkey, int* __restrict__ winner,
                                    int M, int C){
  int i = blockIdx.x*256 + threadIdx.x;
  if (i < M){ int s = seg[i]; if (s >= 0 && s < C) atomicAdd(&counts[s], 1); }
  if (i < C){ int t = pdgkey[i]; if (t >= 0 && t < C) atomicMax(&winner[t], i); }
}

__global__ __launch_bounds__(1024) void scan1_kernel(const int* __restrict__ counts,
    int* __restrict__ loc, int* __restrict__ btot, int C){
  __shared__ int wtot[16];
  __shared__ int wexcl[16];
  int tid = threadIdx.x, lane = tid & 63, wv = tid >> 6;
  int i = blockIdx.x*1024 + tid;
  int v = (i < C) ? counts[i] : 0;
  int x = v;
  #pragma unroll
  for (int d2 = 1; d2 < 64; d2 <<= 1){
    int t = __shfl_up(x, d2, 64);
    if (lane >= d2) x += t;
  }
  if (lane == 63) wtot[wv] = x;
  __syncthreads();
  if (wv == 0 && lane < 16){
    int t = wtot[lane]; int y = t;
    #pragma unroll
    for (int d2 = 1; d2 < 16; d2 <<= 1){
      int u = __shfl_up(y, d2, 64);
      if (lane >= d2) y += u;
    }
    wexcl[lane] = y - t;
    if (lane == 15) btot[blockIdx.x] = y;
  }
  __syncthreads();
  if (i < C) loc[i] = wexcl[wv] + x - v;
}

__global__ void scan2_kernel(const int* __restrict__ btot, int* __restrict__ bexcl,
                             int nb, int* __restrict__ offsets, int C){
  int lane = threadIdx.x;             // 64 threads, nb <= 64
  int v = (lane < nb) ? btot[lane] : 0;
  int x = v;
  #pragma unroll
  for (int d2 = 1; d2 < 64; d2 <<= 1){
    int t = __shfl_up(x, d2, 64);
    if (lane >= d2) x += t;
  }
  if (lane < nb) bexcl[lane] = x - v;
  if (lane == 63) offsets[C] = x;     // grand total
}

__global__ void scan3_kernel(const int* __restrict__ loc, const int* __restrict__ bexcl,
                             int* __restrict__ offsets, int* __restrict__ pos, int C){
  int i = blockIdx.x*256 + threadIdx.x;
  if (i < C){ int o = loc[i] + bexcl[i >> 10]; offsets[i] = o; pos[i] = o; }
}

// rows[p] = astkey[i]: store the enc row id directly.
__global__ void fill_kernel(const int* __restrict__ seg, const int* __restrict__ astkey,
                            int* __restrict__ pos, int* __restrict__ rows, int M, int C){
  int i = blockIdx.x*256 + threadIdx.x;
  if (i < M){
    int s = seg[i];
    if (s >= 0 && s < C){ int p = atomicAdd(&pos[s], 1); rows[p] = astkey[i]; }
  }
}

// ---------------- merged weight prep ----------------
__global__ __launch_bounds__(256) void prep_weights(
    const float* __restrict__ Wq, const float* __restrict__ Wk,
    const float* __restrict__ Wv, const float* __restrict__ Wo,
    const float* __restrict__ bq, const float* __restrict__ bk,
    const float* __restrict__ bv,
    ushort* __restrict__ Wq16, ushort* __restrict__ Wk16, ushort* __restrict__ Wv16,
    ushort* __restrict__ WoT16,
    float* __restrict__ wqbk, float* __restrict__ bvo,
    float* __restrict__ bqk, float* __restrict__ cbh){
  __shared__ float t[64][65];
  int bid = blockIdx.x, tid = threadIdx.x;
  if (bid < 256){
    int id = bid*256 + tid;
    Wq16[id] = f2bf(Wq[id]);
    Wk16[id] = f2bf(Wk[id]);
    Wv16[id] = f2bf(Wv[id]);
  } else if (bid < 269){
    int id = (bid - 256)*256 + tid;
    if (id < 1024){
      int h = id >> 8, k = id & 255;
      float s = 0.f;
      for (int d = 0; d < DH; d++) s += Wq[(size_t)k*256 + h*64 + d] * bk[h*64 + d];
      wqbk[id] = s;
    } else if (id < 2048){
      int tt = id - 1024; int h = tt >> 8, o = tt & 255;
      float s = 0.f;
      for (int d = 0; d < DH; d++) s += bv[h*64 + d] * Wo[(size_t)(h*64 + d)*256 + o];
      bvo[tt] = s;
    } else if (id < 3072){
      int tt = id - 2048; int h = tt >> 8, e = tt & 255;
      float s = 0.f;
      for (int d = 0; d < DH; d++) s += bq[h*64 + d] * Wk[(size_t)e*256 + h*64 + d];
      bqk[tt] = s;
    } else if (id < 3076){
      int h = id - 3072;
      float s = 0.f;
      for (int d = 0; d < DH; d++) s += bq[h*64 + d] * bk[h*64 + d];
      cbh[h] = s;
    }
  } else {
    int b2 = bid - 269;
    int bx = b2 & 3, by = b2 >> 2;
    int r = tid >> 6, cc = tid & 63;
    #pragma unroll
    for (int rr = 0; rr < 64; rr += 4)
      t[rr + r][cc] = Wo[(size_t)(by*64 + rr + r)*256 + bx*64 + cc];
    __syncthreads();
    #pragma unroll
    for (int rr = 0; rr < 64; rr += 4)
      WoT16[(size_t)(bx*64 + rr + r)*256 + by*64 + cc] = f2bf(t[cc][rr + r]);
  }
}

// ---------------- gather attn_keys rows -> bf16 A matrix + qb precompute ----------------
__global__ void gather_ag(const float* __restrict__ enc, const int* __restrict__ rootval,
                          const int* __restrict__ winner,
                          const float* __restrict__ wqbk, const float* __restrict__ cbh,
                          ushort* __restrict__ Ag, float* __restrict__ qb, int C){
  int id = blockIdx.x*256 + threadIdx.x;      // C*64 total
  int c = id >> 6, g = id & 63;
  if (c >= C) return;
  int w = winner[c];
  float4 v = make_float4(0.f, 0.f, 0.f, 0.f);
  if (w >= 0) v = *(const float4*)(enc + (size_t)rootval[w]*D + g*4);
  ushort4 u; u.x = f2bf(v.x); u.y = f2bf(v.y); u.z = f2bf(v.z); u.w = f2bf(v.w);
  *(ushort4*)(Ag + (size_t)c*D + g*4) = u;
  float b0 = bf2f(u.x), b1 = bf2f(u.y), b2 = bf2f(u.z), b3 = bf2f(u.w);
  float pv[4];
  #pragma unroll
  for (int h = 0; h < 4; h++){
    float4 wv = *(const float4*)(wqbk + h*256 + g*4);
    float p = b0*wv.x + b1*wv.y + b2*wv.z + b3*wv.w;
    p = redux32(p);
    p += __shfl_xor(p, 32, 64);
    pv[h] = p;
  }
  if (g < 4) qb[c*4 + g] = pv[g] + cbh[g];
}

// ---------------- unified bf16 MFMA GEMM (64x64 tiles — proven best for these shapes) ----------------
template<bool OUT_BF16>
__global__ __launch_bounds__(256) void mfma_gemm(
    const ushort* __restrict__ A, int sA, int acol_h,
    const ushort* __restrict__ Bt, int sBt, int btrow_h, int btcol_h,
    void* __restrict__ Out, int sOut, int outrow_h, int outcol_h,
    int M, int K,
    const float* __restrict__ bias, const float* __restrict__ beta4,
    const float* __restrict__ bvo4){
  __shared__ __align__(16) ushort As[64][72];
  __shared__ __align__(16) ushort Bs[64][72];
  int tid = threadIdx.x;
  int hz = blockIdx.z;
  int m0 = blockIdx.x*64;
  int acol0  = acol_h*hz;
  int btrow0 = blockIdx.y*64 + btrow_h*hz;
  int btcol0 = btcol_h*hz;
  int outrow0 = outrow_h*hz;
  int outcol0 = blockIdx.y*64 + outcol_h*hz;
  int w = tid >> 6, lane = tid & 63, quad = lane >> 4, l16 = lane & 15;
  int r1 = tid >> 3, c8 = (tid & 7)*8;
  f32x4 acc[4] = {};
  for (int k0 = 0; k0 < K; k0 += 64){
    const ushort* ga = A + (size_t)(m0 + r1)*sA + acol0 + k0 + c8;
    uint4 v1 = make_uint4(0,0,0,0), v2 = make_uint4(0,0,0,0);
    if (m0 + r1 < M)      v1 = *(const uint4*)ga;
    if (m0 + r1 + 32 < M) v2 = *(const uint4*)(ga + (size_t)32*sA);
    *(uint4*)&As[r1][c8]      = v1;
    *(uint4*)&As[r1+32][c8]   = v2;
    const ushort* gb = Bt + (size_t)(btrow0 + r1)*sBt + btcol0 + k0 + c8;
    *(uint4*)&Bs[r1][c8]      = *(const uint4*)gb;
    *(uint4*)&Bs[r1+32][c8]   = *(const uint4*)(gb + (size_t)32*sBt);
    __syncthreads();
    #pragma unroll
    for (int ks = 0; ks < 2; ks++){
      bf16x8 b = *(const bf16x8*)&Bs[w*16 + l16][ks*32 + quad*8];
      #pragma unroll
      for (int mt = 0; mt < 4; mt++){
        bf16x8 a = *(const bf16x8*)&As[mt*16 + l16][ks*32 + quad*8];
        acc[mt] = __builtin_amdgcn_mfma_f32_16x16x32_bf16(a, b, acc[mt], 0, 0, 0);
      }
    }
    __syncthreads();
  }
  int col = outcol0 + w*16 + l16;
  int bcol = btrow0 + w*16 + l16;
  float bval = bias ? bias[bcol] : 0.f;
  #pragma unroll
  for (int mt = 0; mt < 4; mt++){
    #pragma unroll
    for (int r = 0; r < 4; r++){
      int row = m0 + mt*16 + quad*4 + r;
      if (row < M){
        float v = acc[mt][r] + bval;
        if (bvo4){
          v += beta4[row*4+0]*bvo4[0*256 + bcol] + beta4[row*4+1]*bvo4[1*256 + bcol]
             + beta4[row*4+2]*bvo4[2*256 + bcol] + beta4[row*4+3]*bvo4[3*256 + bcol];
        }
        if (OUT_BF16) ((ushort*)Out)[(size_t)(outrow0 + row)*sOut + col] = f2bf(v);
        else          ((float*)Out)[(size_t)(outrow0 + row)*sOut + col] = v;
      }
    }
  }
}

// ---------------- fused per-segment attention pooling ----------------
// One segment per HALF-WAVE (8 segments per 256-thread block). 4 members per iteration
// with 4-row prefetch (8 float4 loads in flight) -> 2x memory-level parallelism vs the
// 2-member version; per-member VALU cost unchanged.
__global__ __launch_bounds__(256) void seg_attn(const float* __restrict__ enc,
    const int* __restrict__ rows, const int* __restrict__ offsets,
    const ushort* __restrict__ qk16, const float* __restrict__ qb,
    ushort* __restrict__ Shat16, float* __restrict__ beta, int C){
  int lane = threadIdx.x & 63, wave = threadIdx.x >> 6;
  int half = lane >> 5, sl = lane & 31;
  int c = blockIdx.x*8 + wave*2 + half;
  if (c >= C) return;
  float qk[4][8];
  const ushort* qkp = qk16 + (size_t)c*1024 + sl*8;
  #pragma unroll
  for (int h = 0; h < 4; h++){
    uint4 u = *(const uint4*)(qkp + h*256);
    qk[h][0]=__uint_as_float(u.x<<16); qk[h][1]=__uint_as_float(u.x&0xffff0000u);
    qk[h][2]=__uint_as_float(u.y<<16); qk[h][3]=__uint_as_float(u.y&0xffff0000u);
    qk[h][4]=__uint_as_float(u.z<<16); qk[h][5]=__uint_as_float(u.z&0xffff0000u);
    qk[h][6]=__uint_as_float(u.w<<16); qk[h][7]=__uint_as_float(u.w&0xffff0000u);
  }
  float4 qbv = *(const float4*)(qb + (size_t)c*4);
  float qbh[4] = {qbv.x, qbv.y, qbv.z, qbv.w};
  int off = offsets[c];
  int n = offsets[c+1] - off;
  float S[4][8] = {};
  float l[4] = {0.f, 0.f, 0.f, 0.f};
  int hbase = half*32;
  for (int base = 0; base < n; base += 32){
    int cnt = min(32, n - base);
    int xrow = 0;
    if (sl < cnt) xrow = rows[off + base + sl];
    float4 x0[4], x1[4];
    #pragma unroll
    for (int m = 0; m < 4; m++){
      int idx = (m < cnt) ? m : (cnt - 1);
      int r = __shfl(xrow, hbase + idx, 64);
      const float* p = enc + (size_t)r*256 + sl*8;
      x0[m] = *(const float4*)p;
      x1[m] = *(const float4*)(p + 4);
    }
    for (int j = 0; j < cnt; j += 4){
      float4 n0[4], n1[4];
      #pragma unroll
      for (int m = 0; m < 4; m++){ n0[m] = x0[m]; n1[m] = x1[m]; }
      if (j + 4 < cnt){
        #pragma unroll
        for (int m = 0; m < 4; m++){
          int k = j + 4 + m; k = (k < cnt) ? k : (cnt - 1);
          int r = __shfl(xrow, hbase + k, 64);
          const float* p = enc + (size_t)r*256 + sl*8;
          n0[m] = *(const float4*)p;
          n1[m] = *(const float4*)(p + 4);
        }
      }
      float pm[4][4];
      #pragma unroll
      for (int m = 0; m < 4; m++){
        #pragma unroll
        for (int h = 0; h < 4; h++){
          pm[m][h] = x0[m].x*qk[h][0] + x0[m].y*qk[h][1] + x0[m].z*qk[h][2] + x0[m].w*qk[h][3]
                   + x1[m].x*qk[h][4] + x1[m].y*qk[h][5] + x1[m].z*qk[h][6] + x1[m].w*qk[h][7];
        }
      }
      #pragma unroll
      for (int m = 0; m < 4; m++){
        #pragma unroll
        for (int h = 0; h < 4; h++) pm[m][h] = redux32(pm[m][h]);
      }
      #pragma unroll
      for (int m = 0; m < 4; m++){
        bool valid = (j + m) < cnt;
        #pragma unroll
        for (int h = 0; h < 4; h++)
          pm[m][h] = valid ? __expf((pm[m][h] + qbh[h]) * 0.125f) : 0.f;
      }
      #pragma unroll
      for (int h = 0; h < 4; h++)
        l[h] += (pm[0][h] + pm[1][h]) + (pm[2][h] + pm[3][h]);
      #pragma unroll
      for (int m = 0; m < 4; m++){
        #pragma unroll
        for (int h = 0; h < 4; h++){
          float e = pm[m][h];
          S[h][0] += e*x0[m].x; S[h][1] += e*x0[m].y;
          S[h][2] += e*x0[m].z; S[h][3] += e*x0[m].w;
          S[h][4] += e*x1[m].x; S[h][5] += e*x1[m].y;
          S[h][6] += e*x1[m].z; S[h][7] += e*x1[m].w;
        }
      }
      #pragma unroll
      for (int m = 0; m < 4; m++){ x0[m] = n0[m]; x1[m] = n1[m]; }
    }
  }
  float inv[4];
  #pragma unroll
  for (int h = 0; h < 4; h++) inv[h] = 1.f / (l[h] + 1e-9f);
  ushort* sp = Shat16 + (size_t)c*1024 + sl*8;
  #pragma unroll
  for (int h = 0; h < 4; h++){
    float ih = inv[h];
    uint4 o;
    o.x = (uint)f2bf(S[h][0]*ih) | ((uint)f2bf(S[h][1]*ih) << 16);
    o.y = (uint)f2bf(S[h][2]*ih) | ((uint)f2bf(S[h][3]*ih) << 16);
    o.z = (uint)f2bf(S[h][4]*ih) | ((uint)f2bf(S[h][5]*ih) << 16);
    o.w = (uint)f2bf(S[h][6]*ih) | ((uint)f2bf(S[h][7]*ih) << 16);
    *(uint4*)(sp + h*256) = o;
  }
  if (sl == 0){
    beta[c*4+0] = l[0] / (l[0] + 1e-9f);
    beta[c*4+1] = l[1] / (l[1] + 1e-9f);
    beta[c*4+2] = l[2] / (l[2] + 1e-9f);
    beta[c*4+3] = l[3] / (l[3] + 1e-9f);
  }
}

extern "C" void kernel_launch(void* const* d_in, const int* in_sizes, int n_in,
                              void* d_out, int out_size, void* d_ws, size_t ws_size,
                              hipStream_t stream) {
  const float* enc    = (const float*)d_in[0];
  const int*   astkey = (const int*)d_in[1];
  const int*   seg    = (const int*)d_in[2];
  const int*   pdgkey = (const int*)d_in[3];
  const int*   pdgval = (const int*)d_in[4];
  const float* Wq = (const float*)d_in[6];
  const float* bq = (const float*)d_in[7];
  const float* Wk = (const float*)d_in[8];
  const float* bk = (const float*)d_in[9];
  const float* Wv = (const float*)d_in[10];
  const float* bv = (const float*)d_in[11];
  const float* Wo = (const float*)d_in[12];
  const float* bo = (const float*)d_in[13];
  float* out = (float*)d_out;
  const int M = in_sizes[1];
  const int C = in_sizes[3];

  char* p = (char*)d_ws;
  auto alloc = [&](size_t bytes) -> void* {
    void* r = (void*)p;
    p += (bytes + 255) / 256 * 256;
    return r;
  };
  ushort* Ag      = (ushort*)alloc((size_t)C * D * 2);
  ushort* qk16    = (ushort*)alloc((size_t)C * H * D * 2);
  ushort* Shat16  = (ushort*)alloc((size_t)C * H * D * 2);
  float*  beta    = (float*)alloc((size_t)C * H * 4);
  float*  qb      = (float*)alloc((size_t)C * H * 4);
  ushort* Wq16    = (ushort*)alloc((size_t)D * D * 2);
  ushort* Wk16    = (ushort*)alloc((size_t)D * D * 2);
  ushort* Wv16    = (ushort*)alloc((size_t)D * D * 2);
  ushort* WoT16   = (ushort*)alloc((size_t)D * D * 2);
  ushort* Gt16    = (ushort*)alloc((size_t)H * D * D * 2);
  ushort* Zt16    = (ushort*)alloc((size_t)D * H * D * 2);
  float*  wqbk    = (float*)alloc((size_t)H * D * 4);
  float*  bvo     = (float*)alloc((size_t)H * NOUT * 4);
  float*  bqk     = (float*)alloc((size_t)H * D * 4);
  float*  cbh     = (float*)alloc((size_t)H * 4);
  int*   winner   = (int*)alloc((size_t)C * 4);
  int*   counts   = (int*)alloc((size_t)C * 4);
  int*   loc      = (int*)alloc((size_t)C * 4);
  int*   btot     = (int*)alloc((size_t)64 * 4);
  int*   bexcl    = (int*)alloc((size_t)64 * 4);
  int*   offsets  = (int*)alloc((size_t)(C + 1) * 4);
  int*   pos      = (int*)alloc((size_t)C * 4);
  int*   rows     = (int*)alloc((size_t)M * 4);

  hipMemsetAsync(winner, 0xFF, (size_t)C * 4, stream);
  hipMemsetAsync(counts, 0, (size_t)C * 4, stream);

  int gC = (C + 255) / 256, gM = (M + 255) / 256;
  int gMC = ((M > C ? M : C) + 255) / 256;
  int nb1024 = (C + 1023) / 1024;
  count_winner_kernel<<<gMC, 256, 0, stream>>>(seg, counts, pdgkey, winner, M, C);
  scan1_kernel<<<nb1024, 1024, 0, stream>>>(counts, loc, btot, C);
  scan2_kernel<<<1, 64, 0, stream>>>(btot, bexcl, nb1024, offsets, C);
  scan3_kernel<<<gC, 256, 0, stream>>>(loc, bexcl, offsets, pos, C);
  fill_kernel<<<gM, 256, 0, stream>>>(seg, astkey, pos, rows, M, C);

  prep_weights<<<285, 256, 0, stream>>>(Wq, Wk, Wv, Wo, bq, bk, bv,
                                        Wq16, Wk16, Wv16, WoT16, wqbk, bvo, bqk, cbh);

  // Gt[(h,e)][k] = sum_d Wq[k,64h+d]*Wk[e,64h+d]
  mfma_gemm<true><<<dim3(4,4,4), 256, 0, stream>>>(
      Wk16, D, DH,  Wq16, D, 0, DH,  Gt16, D, D, 0,  D, DH, nullptr, nullptr, nullptr);
  // Zt[o][(h,j)] = sum_d Wv[j,64h+d]*Wo[64h+d,o]
  mfma_gemm<true><<<dim3(4,4,4), 256, 0, stream>>>(
      WoT16, D, DH,  Wv16, D, 0, DH,  Zt16, H*D, 0, D,  D, DH, nullptr, nullptr, nullptr);

  gather_ag<<<(C*64 + 255)/256, 256, 0, stream>>>(enc, pdgval, winner, wqbk, cbh,
                                                  Ag, qb, C);

  int mt = (C + 63) / 64;
  // qk16[c,(h,e)] = Ag[c,:] @ Gt[(h,e),:] + bqk[(h,e)]
  mfma_gemm<true><<<dim3(mt,4,4), 256, 0, stream>>>(
      Ag, D, 0,  Gt16, D, D, 0,  qk16, H*D, 0, D,  C, D, bqk, nullptr, nullptr);

  seg_attn<<<(C + 7)/8, 256, 0, stream>>>(enc, rows, offsets, qk16, qb,
                                          Shat16, beta, C);

  // out[c,o] = Shat[c,:] @ Zt[o,:] + bo[o] + sum_h beta[c,h]*bvo[h,o]
  mfma_gemm<false><<<dim3(mt,4,1), 256, 0, stream>>>(
      Shat16, H*D, 0,  Zt16, H*D, 0, 0,  out, NOUT, 0, 0,  C, H*D, bo, beta, bvo);
}